// Round 14
// baseline (1166.368 us; speedup 1.0000x reference)
//
#include <hip/hip_runtime.h>
#include <hip/hip_bf16.h>

// ---------------------------------------------------------------------------
// Multimodal LSTM (x3) -> concat -> PTP layer1 (8 windows, rank 16) -> PTP layer2
// Round 14: r13 fusion with the hp window-stride bug fixed (96*1024 -> 96*4096
// u32 in the fused ptp1 A-operand base). Blocks 0-47 = proven lstm6 + window
// release flags; blocks 48-255 = ptp1 tiles gated on flags[n]==48.
// ---------------------------------------------------------------------------

namespace {
constexpr int kB  = 256;
constexpr int kT  = 32;
constexpr int kH  = 256;
constexpr int k4H = 1024;
constexpr int kNW = 8;
constexpr int kR  = 16;
constexpr int kO0 = 128;
constexpr int kO1 = 64;
constexpr int kD1 = 3073;   // 4*768 + 1
constexpr int kD2 = 1025;   // 8*128 + 1
}

typedef __attribute__((ext_vector_type(8))) short short8;   // 8 bf16 (4 VGPRs)
typedef __attribute__((ext_vector_type(4))) float f32x4;    // MFMA acc
typedef __attribute__((ext_vector_type(4))) unsigned int u32x4;

typedef const __attribute__((address_space(1))) unsigned int* gas_u32p;
typedef __attribute__((address_space(3))) unsigned int* las_u32p;

__device__ __forceinline__ unsigned int pack2bf(float a, float b) {
    unsigned int ua = __builtin_bit_cast(unsigned int, a);
    unsigned int ub = __builtin_bit_cast(unsigned int, b);
    return (ua >> 16) | (ub & 0xffff0000u);
}
__device__ __forceinline__ float bflo(unsigned int u) {
    return __builtin_bit_cast(float, u << 16);
}
__device__ __forceinline__ float bfhi(unsigned int u) {
    return __builtin_bit_cast(float, u & 0xffff0000u);
}
__device__ __forceinline__ float sigm(float x) {
    return 1.f / (1.f + __expf(-x));
}
__device__ __forceinline__ float tanh_fast(float x) {
    float a = fabsf(x);
    float t = 1.f - 2.f / (__expf(2.f * a) + 1.f);
    return copysignf(t, x);
}
__device__ __forceinline__ uint2 gload2u(const unsigned short* p) {
    uint2 r;
    asm volatile("global_load_dwordx2 %0, %1, off" : "=v"(r) : "v"(p) : "memory");
    return r;
}

// ---------------- Fused: 3x input-projection GEMMs + W_hh fragment pack + flag init.
__global__ __launch_bounds__(512)
void k_mm_all(const float* __restrict__ A0, const float* __restrict__ A1,
              const float* __restrict__ A2,
              const float* __restrict__ W0, const float* __restrict__ W1,
              const float* __restrict__ W2,
              const float* __restrict__ bi0, const float* __restrict__ bi1,
              const float* __restrict__ bi2,
              const float* __restrict__ bh0, const float* __restrict__ bh1,
              const float* __restrict__ bh2,
              unsigned short* __restrict__ C0, unsigned short* __restrict__ C1,
              unsigned short* __restrict__ C2,
              const float* __restrict__ wa, const float* __restrict__ wv,
              const float* __restrict__ wtx, unsigned int* __restrict__ wfrag,
              unsigned int* __restrict__ flags) {
    const int bx  = blockIdx.x;
    const int tid = threadIdx.x;

    if (bx >= 768) {
        if (bx == 768 && tid < 8) flags[tid] = 0u;   // per-launch window flags
        // ---- W_hh fragment pack: g = (net, w, s, gate, lane)
        int g = (bx - 768) * 512 + tid;     // 0 .. 98303
        int l  = g & 63;
        int gt = (g >> 6) & 3;
        int s  = (g >> 8) & 7;
        int w  = (g >> 11) & 15;
        int net = g >> 15;
        const float* W = (net == 0) ? wa : (net == 1) ? wv : wtx;
        const int col = gt * 256 + w * 16 + (l & 15);
        const int k0  = s * 32 + (l >> 4) * 8;
        const float* src = W + (size_t)col * 256 + k0;
        float4 f0 = *(const float4*)src;
        float4 f1 = *(const float4*)(src + 4);
        u32x4 v = { pack2bf(f0.x, f0.y), pack2bf(f0.z, f0.w),
                    pack2bf(f1.x, f1.y), pack2bf(f1.z, f1.w) };
        *(u32x4*)&wfrag[(size_t)g * 4] = v;
        return;
    }

    // ---- input projection GEMM (permuted bf16 output)
    const int net = bx >> 8;
    const int mt  = (bx & 255) >> 3;
    const int nt  = bx & 7;
    const float* A  = (net == 0) ? A0 : (net == 1) ? A1 : A2;
    const float* W  = (net == 0) ? W0 : (net == 1) ? W1 : W2;
    const float* b1 = (net == 0) ? bi0 : (net == 1) ? bi1 : bi2;
    const float* b2 = (net == 0) ? bh0 : (net == 1) ? bh1 : bh2;
    unsigned short* C = (net == 0) ? C0 : (net == 1) ? C1 : C2;
    const int K = (net == 0) ? 128 : (net == 1) ? 256 : 768;

    __shared__ __align__(16) unsigned int As[256 * 20];
    __shared__ __align__(16) unsigned int Bs[128 * 20];
    const int lane = tid & 63;
    const int wid  = tid >> 6;
    const int wm   = wid >> 1, wn = wid & 1;
    const int m0 = mt * 256, n0 = nt * 128;
    const int nstep = K >> 5;

    const int ar = tid >> 1, akq = (tid & 1) * 16;
    const int br = tid >> 2, bkq = (tid & 3) * 8;
    const float* ap = A + (size_t)(m0 + ar) * K + akq;
    const int nn = n0 + br;
    const int worow = (nn & 3) * 256 + (nn >> 6) * 16 + ((nn >> 2) & 15);
    const float* wp = W + (size_t)worow * K + bkq;

    float4 aR[4], bR[2];
    auto loadA = [&](int s) {
#pragma unroll
        for (int i = 0; i < 4; ++i) aR[i] = *(const float4*)(ap + s * 32 + i * 4);
    };
    auto loadB = [&](int s) {
#pragma unroll
        for (int i = 0; i < 2; ++i) bR[i] = *(const float4*)(wp + s * 32 + i * 4);
    };

    f32x4 acc[4][4];
#pragma unroll
    for (int i = 0; i < 4; ++i)
#pragma unroll
        for (int j = 0; j < 4; ++j) acc[i][j] = (f32x4){0.f, 0.f, 0.f, 0.f};

    loadA(0); loadB(0);
    for (int s = 0; s < nstep; ++s) {
        __syncthreads();
        {
            u32x4 w0 = { pack2bf(aR[0].x, aR[0].y), pack2bf(aR[0].z, aR[0].w),
                         pack2bf(aR[1].x, aR[1].y), pack2bf(aR[1].z, aR[1].w) };
            u32x4 w1 = { pack2bf(aR[2].x, aR[2].y), pack2bf(aR[2].z, aR[2].w),
                         pack2bf(aR[3].x, aR[3].y), pack2bf(aR[3].z, aR[3].w) };
            *(u32x4*)&As[ar * 20 + (akq >> 1)]     = w0;
            *(u32x4*)&As[ar * 20 + (akq >> 1) + 4] = w1;
            u32x4 v0 = { pack2bf(bR[0].x, bR[0].y), pack2bf(bR[0].z, bR[0].w),
                         pack2bf(bR[1].x, bR[1].y), pack2bf(bR[1].z, bR[1].w) };
            *(u32x4*)&Bs[br * 20 + (bkq >> 1)] = v0;
        }
        __syncthreads();
        if (s + 1 < nstep) { loadA(s + 1); loadB(s + 1); }
        short8 af[4], bf[4];
#pragma unroll
        for (int i = 0; i < 4; ++i)
            af[i] = __builtin_bit_cast(short8,
                *(const u32x4*)&As[(wm * 64 + i * 16 + (lane & 15)) * 20 + (lane >> 4) * 4]);
#pragma unroll
        for (int j = 0; j < 4; ++j)
            bf[j] = __builtin_bit_cast(short8,
                *(const u32x4*)&Bs[(wn * 64 + j * 16 + (lane & 15)) * 20 + (lane >> 4) * 4]);
#pragma unroll
        for (int i = 0; i < 4; ++i)
#pragma unroll
            for (int j = 0; j < 4; ++j)
                acc[i][j] = __builtin_amdgcn_mfma_f32_16x16x32_bf16(af[i], bf[j], acc[i][j], 0, 0, 0);
    }
#pragma unroll
    for (int i = 0; i < 4; ++i) {
#pragma unroll
        for (int j = 0; j < 4; ++j) {
            const int col  = n0 + wn * 64 + j * 16 + (lane & 15);
            const int ocol = (col & 3) * 256 + (col >> 6) * 16 + ((col >> 2) & 15);
            const float badd = b1[ocol] + b2[ocol];
#pragma unroll
            for (int e = 0; e < 4; ++e) {
                const int row = m0 + wm * 64 + i * 16 + (lane >> 4) * 4 + e;
                const float v = acc[i][j][e] + badd;
                C[(size_t)row * 1024 + col] =
                    (unsigned short)(__builtin_bit_cast(unsigned int, v) >> 16);
            }
        }
    }
}

// ---------------- Fused LSTM + PTP1:
// Blocks 0..47: lstm6 recurrence (r8/r10-proven) + per-window release flags.
// Blocks 48..255: ptp1 tiles (r,n,bz), gated on flags[n]==48.
__global__ __launch_bounds__(1024, 4)
void k_lstm_ptp1(const unsigned short* __restrict__ xp_a, const unsigned short* __restrict__ xp_v,
                 const unsigned short* __restrict__ xp_t, const unsigned int* __restrict__ wfrag,
                 unsigned short* __restrict__ hp, const float* __restrict__ factor,
                 float* __restrict__ z1, unsigned int* __restrict__ flags) {
    __shared__ __align__(16) unsigned short hA[8192];     // lstm: 2x8KB swizzled; ptp1: Bs alias
    __shared__ __align__(16) unsigned int Wring[32768];   // lstm: 128 KB DMA ring

    const int bx  = blockIdx.x;
    const int tid = threadIdx.x;

    if (bx >= 48) {
        // ================= PTP1 MFMA GEMM (full K, N-split, BK=64) =================
        if (tid >= 512) return;
        unsigned char* Bs = (unsigned char*)hA;   // 64*144 = 9216 B < 16 KB
        const int lane = tid & 63;
        const int wid  = tid >> 6;
        const int bo = tid & 63;           // staged o (local)
        const int bc = tid >> 6;           // d-chunk 0..7

        for (int ti = bx - 48; ti < 256; ti += 208) {
            const int n  = ti >> 5;
            const int r  = (ti >> 1) & 15;
            const int bz = ti & 1;

            // wait for window n (48 lstm blocks released it)
            if (tid == 0) {
                while (__hip_atomic_load(&flags[n], __ATOMIC_ACQUIRE,
                                         __HIP_MEMORY_SCOPE_AGENT) < 48u)
                    __builtin_amdgcn_s_sleep(32);
            }
            __syncthreads();
            __builtin_amdgcn_fence(__ATOMIC_ACQUIRE, "agent");

            const float* fp = factor
                + ((size_t)(n * kR + r) * kD1 + 1 + bc * 8) * kO0 + bz * 64 + bo;
            const unsigned int* ha = (const unsigned int*)hp
                + (size_t)n * 96 * 4096 + lane * 4;   // FIX: window stride 96*4096 u32

            f32x4 acc[2][4];
#pragma unroll
            for (int i = 0; i < 2; ++i)
#pragma unroll
                for (int j = 0; j < 4; ++j) acc[i][j] = (f32x4){0.f, 0.f, 0.f, 0.f};

            u32x4 pkb[2];
            u32x4 af[2][2][2];                 // [buf][ks][mfrag]
            auto loadB = [&](int s, int qq) {
                float rv[8];
#pragma unroll
                for (int e = 0; e < 8; ++e)
                    rv[e] = fp[((size_t)s * 64 + e) * kO0];
                pkb[qq] = (u32x4){ pack2bf(rv[0], rv[1]), pack2bf(rv[2], rv[3]),
                                   pack2bf(rv[4], rv[5]), pack2bf(rv[6], rv[7]) };
            };
            auto loadA = [&](int s, int qq) {
#pragma unroll
                for (int ks = 0; ks < 2; ++ks)
#pragma unroll
                    for (int i = 0; i < 2; ++i)
                        af[qq][ks][i] = *(const u32x4*)(ha
                            + ((size_t)(s * 32 + ks * 16 + wid * 2 + i)) * 256);
            };
            loadB(0, 0); loadA(0, 0);
#pragma unroll 2
            for (int s = 0; s < 48; ++s) {
                const int qq = s & 1;
                __syncthreads();
                *(u32x4*)(Bs + bo * 144 + bc * 16) = pkb[qq];
                __syncthreads();
                if (s + 1 < 48) { loadB(s + 1, qq ^ 1); loadA(s + 1, qq ^ 1); }
                short8 bf[2][4];
#pragma unroll
                for (int ks = 0; ks < 2; ++ks)
#pragma unroll
                    for (int j = 0; j < 4; ++j)
                        bf[ks][j] = __builtin_bit_cast(short8,
                            *(const u32x4*)(Bs + (j * 16 + (lane & 15)) * 144
                                            + ks * 64 + (lane >> 4) * 16));
#pragma unroll
                for (int ks = 0; ks < 2; ++ks)
#pragma unroll
                    for (int i = 0; i < 2; ++i)
#pragma unroll
                        for (int j = 0; j < 4; ++j)
                            acc[i][j] = __builtin_amdgcn_mfma_f32_16x16x32_bf16(
                                __builtin_bit_cast(short8, af[qq][ks][i]), bf[ks][j],
                                acc[i][j], 0, 0, 0);
            }
            const size_t zb = (size_t)n * 256;
#pragma unroll
            for (int i = 0; i < 2; ++i) {
#pragma unroll
                for (int j = 0; j < 4; ++j) {
                    const int col = bz * 64 + j * 16 + (lane & 15);
#pragma unroll
                    for (int e = 0; e < 4; ++e) {
                        const int row = (wid * 2 + i) * 16 + (lane >> 4) * 4 + e;
                        z1[((zb + row) * kR + r) * kO0 + col] = acc[i][j][e];
                    }
                }
            }
            __syncthreads();   // protect Bs before next tile's staging
        }
        return;
    }

    // ================= LSTM recurrence (lstm6, verbatim + window releases) =========
    const int bg  = bx & 15;               // 0..15
    const int net = bx >> 4;               // 0=audio,1=video,2=text
    const int l   = tid & 63;
    const int w   = tid >> 6;              // wave -> dim-slice [16w,16w+16)
    const unsigned short* xp = (net == 0) ? xp_a : (net == 1) ? xp_v : xp_t;
    const int coloff = (net == 0) ? 256 : (net == 1) ? 512 : 0;  // cat=[text,audio,video]

    for (int i = tid; i < 4096; i += 1024) ((unsigned int*)hA)[i] = 0u;

    const int q  = l & 15;
    const int r0 = (l >> 4) * 4;           // first of 4 batch rows this lane owns
    const int d  = w * 16 + q;             // dim within net

    const char* wbase = (const char*)wfrag + (size_t)(net * 16 + w) * 32768 + l * 16;
    unsigned int* wslot = &Wring[w * 2048];

    const unsigned short* xr0 = xp + ((size_t)(bg * 16 + r0) * 32) * 1024 + w * 64 + q * 4;

    const unsigned int rbase = (unsigned int)q * 512;
    const unsigned int rxor  = (unsigned int)(q & 7) << 4;
    const unsigned int kofs  = (unsigned int)(l >> 4) * 16;

    float cc[4] = {0.f, 0.f, 0.f, 0.f};

    auto issue_slab = [&](int slab, int slot) {
#pragma unroll
        for (int g = 0; g < 4; ++g) {
            const void* gp = (const void*)(wbase + slab * 4096 + g * 1024);
            void* lp = (void*)(wslot + slot * 1024 + g * 256);
            __builtin_amdgcn_global_load_lds(
                (gas_u32p)(size_t)gp,
                (las_u32p)(unsigned int)(size_t)lp, 16, 0, 0);
        }
    };

    issue_slab(0, 0);
    issue_slab(1, 1);
    asm volatile("s_waitcnt lgkmcnt(0)" ::: "memory");
    __builtin_amdgcn_s_barrier();

    for (int t = 0; t < kT; ++t) {
        const unsigned short* xr = xr0 + (size_t)t * 1024;
        uint2 xq0 = gload2u(xr);
        uint2 xq1 = gload2u(xr + 32768);
        uint2 xq2 = gload2u(xr + 65536);
        uint2 xq3 = gload2u(xr + 98304);

        const unsigned int rbuf = (unsigned int)(t & 1) * 8192;
        const unsigned int wbuf = 8192u - rbuf;

        f32x4 acc[4];
#pragma unroll
        for (int g = 0; g < 4; ++g) acc[g] = (f32x4){0.f, 0.f, 0.f, 0.f};

#pragma unroll
        for (int s = 0; s < 8; ++s) {
            if (s < 2) asm volatile("s_waitcnt vmcnt(8)" ::: "memory");
            else       asm volatile("s_waitcnt vmcnt(4)" ::: "memory");
            __builtin_amdgcn_sched_barrier(0);
            u32x4 af = *(const u32x4*)((const char*)hA + rbuf + rbase
                                       + (((unsigned)(s * 64) + kofs) ^ rxor));
            const unsigned int* wp = wslot + (s & 1) * 1024;
            u32x4 b0 = *(const u32x4*)(wp + 0 * 256 + l * 4);
            u32x4 b1 = *(const u32x4*)(wp + 1 * 256 + l * 4);
            u32x4 b2 = *(const u32x4*)(wp + 2 * 256 + l * 4);
            u32x4 b3 = *(const u32x4*)(wp + 3 * 256 + l * 4);
            acc[0] = __builtin_amdgcn_mfma_f32_16x16x32_bf16(
                __builtin_bit_cast(short8, af), __builtin_bit_cast(short8, b0), acc[0], 0, 0, 0);
            acc[1] = __builtin_amdgcn_mfma_f32_16x16x32_bf16(
                __builtin_bit_cast(short8, af), __builtin_bit_cast(short8, b1), acc[1], 0, 0, 0);
            acc[2] = __builtin_amdgcn_mfma_f32_16x16x32_bf16(
                __builtin_bit_cast(short8, af), __builtin_bit_cast(short8, b2), acc[2], 0, 0, 0);
            acc[3] = __builtin_amdgcn_mfma_f32_16x16x32_bf16(
                __builtin_bit_cast(short8, af), __builtin_bit_cast(short8, b3), acc[3], 0, 0, 0);
            __builtin_amdgcn_sched_barrier(0);
            issue_slab((s + 2) & 7, s & 1);
        }

        asm volatile("s_waitcnt vmcnt(8)" ::: "memory");
        __builtin_amdgcn_sched_barrier(0);

        float hv[4];
        {
            float gi, gf, gg, go;
            gi = acc[0][0] + bflo(xq0.x); gf = acc[1][0] + bfhi(xq0.x);
            gg = acc[2][0] + bflo(xq0.y); go = acc[3][0] + bfhi(xq0.y);
            cc[0] = sigm(gf) * cc[0] + sigm(gi) * tanh_fast(gg); hv[0] = sigm(go) * tanh_fast(cc[0]);
            gi = acc[0][1] + bflo(xq1.x); gf = acc[1][1] + bfhi(xq1.x);
            gg = acc[2][1] + bflo(xq1.y); go = acc[3][1] + bfhi(xq1.y);
            cc[1] = sigm(gf) * cc[1] + sigm(gi) * tanh_fast(gg); hv[1] = sigm(go) * tanh_fast(cc[1]);
            gi = acc[0][2] + bflo(xq2.x); gf = acc[1][2] + bfhi(xq2.x);
            gg = acc[2][2] + bflo(xq2.y); go = acc[3][2] + bfhi(xq2.y);
            cc[2] = sigm(gf) * cc[2] + sigm(gi) * tanh_fast(gg); hv[2] = sigm(go) * tanh_fast(cc[2]);
            gi = acc[0][3] + bflo(xq3.x); gf = acc[1][3] + bfhi(xq3.x);
            gg = acc[2][3] + bflo(xq3.y); go = acc[3][3] + bfhi(xq3.y);
            cc[3] = sigm(gf) * cc[3] + sigm(gi) * tanh_fast(gg); hv[3] = sigm(go) * tanh_fast(cc[3]);
        }

        const int kk = (t & 3) * 768 + coloff + d;
        const int sp2 = kk >> 5;
        unsigned short* hpb = hp +
            ((((size_t)((t >> 2) * 96 + sp2) * 16 + bg) * 64
              + (unsigned)(r0 | (((kk >> 3) & 3) << 4))) * 8 + (kk & 7));
#pragma unroll
        for (int e = 0; e < 4; ++e) {
            const unsigned short hb =
                (unsigned short)(__builtin_bit_cast(unsigned int, hv[e]) >> 16);
            const int row = r0 + e;
            *(unsigned short*)((char*)hA + wbuf + (unsigned)row * 512
                               + (((unsigned)(2 * d)) ^ (((unsigned)(row & 7)) << 4))) = hb;
            hpb[e * 8] = hb;
        }

        // window boundary: make hp visible device-wide, then arrive
        if ((t & 3) == 3)
            __builtin_amdgcn_fence(__ATOMIC_RELEASE, "agent");
        asm volatile("s_waitcnt lgkmcnt(0)" ::: "memory");
        __builtin_amdgcn_s_barrier();
        if ((t & 3) == 3 && tid == 0)
            __hip_atomic_fetch_add(&flags[t >> 2], 1u, __ATOMIC_RELEASE,
                                   __HIP_MEMORY_SCOPE_AGENT);
    }
}

// ---------------- PTP1 epilogue: barrier-free, 64 threads (o and o+64 per lane)
__global__ __launch_bounds__(64)
void k_ptp1_post(const float* __restrict__ z1, const float* __restrict__ factor,
                 const float* __restrict__ w, const float* __restrict__ bias,
                 float* __restrict__ f1) {
    const int b = blockIdx.x;
    const int n = blockIdx.y;
    const int o = threadIdx.x;   // handles o and o+64
    float sv0[kR], sv1[kR], nrm[kR];
    const size_t zbase = ((size_t)n * kB + b) * kR * kO0;
#pragma unroll
    for (int r = 0; r < kR; ++r) {
        const size_t zo = zbase + r * kO0 + o;
        const size_t fo = (size_t)(n * kR + r) * kD1 * kO0 + o;
        float v0 = z1[zo] + 0.5f * factor[fo];
        float v1 = z1[zo + 64] + 0.5f * factor[fo + 64];
        float a0 = fabsf(v0), a1 = fabsf(v1);
        float s0 = copysignf(a0 * sqrtf(a0), v0);
        float s1 = copysignf(a1 * sqrtf(a1), v1);
        sv0[r] = s0; sv1[r] = s1;
        float t = s0 * s0 + s1 * s1;
#pragma unroll
        for (int off = 1; off < 64; off <<= 1) t += __shfl_xor(t, off, 64);
        nrm[r] = sqrtf(t);
    }
    float out0 = bias[n * kO0 + o];
    float out1 = bias[n * kO0 + o + 64];
#pragma unroll
    for (int r = 0; r < kR; ++r) {
        const float wr = w[n * kR + r];
        out0 += wr * sv0[r] / nrm[r];
        out1 += wr * sv1[r] / nrm[r];
    }
    f1[((size_t)b * kNW + n) * kO0 + o] = out0;
    f1[((size_t)b * kNW + n) * kO0 + o + 64] = out1;
}

// ---------------- PTP2 GEMM (full K, F2 staged in LDS): z2[b,r,o]
__global__ __launch_bounds__(256)
void k_ptp2_gemm(const float* __restrict__ f1flat, const float* __restrict__ factor2,
                 float* __restrict__ z2) {
    const int b0 = blockIdx.x * 32;
    const int r  = blockIdx.y;
    const int tx = threadIdx.x & 63;   // o
    const int ty = threadIdx.x >> 6;   // 0..3
    __shared__ float xs[32][128];
    __shared__ float Fs[128][64];
    float acc[8];
#pragma unroll
    for (int i = 0; i < 8; ++i) acc[i] = 0.f;
    const float* F = factor2 + (size_t)r * kD2 * kO1;

    for (int k0 = 0; k0 < kD2; k0 += 128) {
        const int len = min(128, kD2 - k0);
        {
            const int row = threadIdx.x >> 3;
            const int c0  = (threadIdx.x & 7) * 16;
#pragma unroll
            for (int i = 0; i < 16; ++i) {
                int k = k0 + c0 + i;
                float v = (k == 0) ? 0.5f
                        : (k < kD2 ? f1flat[(size_t)(b0 + row) * 1024 + (k - 1)] : 0.f);
                xs[row][c0 + i] = v;
            }
        }
        {
#pragma unroll
            for (int i = 0; i < 8; ++i) {
                const int u  = threadIdx.x + i * 256;
                const int dd = u >> 4;
                const int oc = (u & 15) * 4;
                float4 v = (k0 + dd < kD2)
                    ? *(const float4*)(F + (size_t)(k0 + dd) * kO1 + oc)
                    : make_float4(0.f, 0.f, 0.f, 0.f);
                *(float4*)&Fs[dd][oc] = v;
            }
        }
        __syncthreads();
        for (int dd = 0; dd < len; ++dd) {
            float wv = Fs[dd][tx];
#pragma unroll
            for (int i = 0; i < 8; ++i) acc[i] = fmaf(xs[ty * 8 + i][dd], wv, acc[i]);
        }
        __syncthreads();
    }
#pragma unroll
    for (int i = 0; i < 8; ++i) {
        const int b = b0 + ty * 8 + i;
        z2[((size_t)b * kR + r) * kO1 + tx] = acc[i];
    }
}

// ---------------- PTP2 epilogue -> final output (B,64) fp32
__global__ __launch_bounds__(64)
void k_ptp2_post(const float* __restrict__ z2, const float* __restrict__ w2,
                 const float* __restrict__ b2, float* __restrict__ out) {
    const int b = blockIdx.x;
    const int o = threadIdx.x;
    float sv[kR], nrm[kR];
#pragma unroll
    for (int r = 0; r < kR; ++r) {
        float v = z2[((size_t)b * kR + r) * kO1 + o];
        float a = fabsf(v);
        float s = copysignf(a * sqrtf(a), v);
        sv[r] = s;
        float t = s * s;
#pragma unroll
        for (int off = 1; off < 64; off <<= 1) t += __shfl_xor(t, off, 64);
        nrm[r] = sqrtf(t);
    }
    float acc = b2[o];
#pragma unroll
    for (int r = 0; r < kR; ++r) acc += w2[r] * sv[r] / nrm[r];
    out[(size_t)b * kO1 + o] = acc;
}

// ---------------------------------------------------------------------------
extern "C" void kernel_launch(void* const* d_in, const int* in_sizes, int n_in,
                              void* d_out, int out_size, void* d_ws, size_t ws_size,
                              hipStream_t stream) {
    const float* audio_x  = (const float*)d_in[0];
    const float* video_x  = (const float*)d_in[1];
    const float* text_x   = (const float*)d_in[2];
    const float* aw_ih    = (const float*)d_in[3];
    const float* aw_hh    = (const float*)d_in[4];
    const float* ab_ih    = (const float*)d_in[5];
    const float* ab_hh    = (const float*)d_in[6];
    const float* vw_ih    = (const float*)d_in[7];
    const float* vw_hh    = (const float*)d_in[8];
    const float* vb_ih    = (const float*)d_in[9];
    const float* vb_hh    = (const float*)d_in[10];
    const float* txw_ih   = (const float*)d_in[11];
    const float* txw_hh   = (const float*)d_in[12];
    const float* txb_ih   = (const float*)d_in[13];
    const float* txb_hh   = (const float*)d_in[14];
    const float* l1_factor = (const float*)d_in[15];
    const float* l1_weight = (const float*)d_in[16];
    const float* l1_bias   = (const float*)d_in[17];
    const float* l2_factor = (const float*)d_in[18];
    const float* l2_weight = (const float*)d_in[19];
    const float* l2_bias   = (const float*)d_in[20];

    float* ws = (float*)d_ws;
    // workspace layout (float-index units):
    //   xp_a [0,4M)  xp_v [4M,8M)  xp_t [8M,12M)   (each 8192x1024 bf16)
    //   hp at 12,582,912 (+3,145,728)   wfrag at 15,728,640 (+393,216)
    //   flags at 16,121,856 (+16)       z1 at 16,121,872 (+4,194,304)
    unsigned short* xp_a = (unsigned short*)ws;
    unsigned short* xp_v = (unsigned short*)(ws + 4194304);
    unsigned short* xp_t = (unsigned short*)(ws + 8388608);
    unsigned short* hp   = (unsigned short*)(ws + 12582912);
    unsigned int* wfrag  = (unsigned int*)(ws + 15728640);
    unsigned int* flags  = (unsigned int*)(ws + 16121856);
    float* z1 = ws + 16121872;                 //  4,194,304  (n,b,r,o)
    // post-LSTM aliases (xp buffers dead by ptp1_post time):
    float* f1 = ws + 8388608;                  //    262,144  (in dead xp_t region)
    float* z2 = ws + 8388608 + 262144;         //    262,144

    // 1) fused: 3x input projections (bf16 out, permuted) + W_hh pack + flag init
    k_mm_all<<<960, 512, 0, stream>>>(audio_x, video_x, text_x,
                                      aw_ih, vw_ih, txw_ih,
                                      ab_ih, vb_ih, txb_ih,
                                      ab_hh, vb_hh, txb_hh,
                                      xp_a, xp_v, xp_t,
                                      aw_hh, vw_hh, txw_hh, wfrag, flags);

    // 2) fused LSTM recurrence + shadow PTP1 (window-flag gated)
    k_lstm_ptp1<<<256, 1024, 0, stream>>>(xp_a, xp_v, xp_t, wfrag, hp,
                                          l1_factor, z1, flags);

    // 3) PTP1 epilogue
    k_ptp1_post<<<dim3(256, 8), 64, 0, stream>>>(z1, l1_factor, l1_weight, l1_bias, f1);

    // 4) PTP layer 2 -> output
    k_ptp2_gemm<<<dim3(8, 16), 256, 0, stream>>>(f1, l2_factor, z2);
    k_ptp2_post<<<256, 64, 0, stream>>>(z2, l2_weight, l2_bias, (float*)d_out);
}

// Round 15
// 407.266 us; speedup vs baseline: 2.8639x; 2.8639x over previous
//
#include <hip/hip_runtime.h>
#include <hip/hip_bf16.h>

// ---------------------------------------------------------------------------
// Multimodal LSTM (x3) -> concat -> PTP layer1 (8 windows, rank 16) -> PTP layer2
// Round 15: restore r12 (419us proven). Fusion of lstm+ptp1 is refuted (r14:
// agent-scope coherence fences invalidate per-XCD L2 -> lstm W-stream dies).
// Single tweak vs r12: ptp2_gemm M-split to 16 rows/block (grid 16x16).
// ---------------------------------------------------------------------------

namespace {
constexpr int kB  = 256;
constexpr int kT  = 32;
constexpr int kH  = 256;
constexpr int k4H = 1024;
constexpr int kNW = 8;
constexpr int kR  = 16;
constexpr int kO0 = 128;
constexpr int kO1 = 64;
constexpr int kD1 = 3073;   // 4*768 + 1
constexpr int kD2 = 1025;   // 8*128 + 1
}

typedef __attribute__((ext_vector_type(8))) short short8;   // 8 bf16 (4 VGPRs)
typedef __attribute__((ext_vector_type(4))) float f32x4;    // MFMA acc
typedef __attribute__((ext_vector_type(4))) unsigned int u32x4;

typedef const __attribute__((address_space(1))) unsigned int* gas_u32p;
typedef __attribute__((address_space(3))) unsigned int* las_u32p;

__device__ __forceinline__ unsigned int pack2bf(float a, float b) {
    unsigned int ua = __builtin_bit_cast(unsigned int, a);
    unsigned int ub = __builtin_bit_cast(unsigned int, b);
    return (ua >> 16) | (ub & 0xffff0000u);
}
__device__ __forceinline__ float bflo(unsigned int u) {
    return __builtin_bit_cast(float, u << 16);
}
__device__ __forceinline__ float bfhi(unsigned int u) {
    return __builtin_bit_cast(float, u & 0xffff0000u);
}
__device__ __forceinline__ float sigm(float x) {
    return 1.f / (1.f + __expf(-x));
}
__device__ __forceinline__ float tanh_fast(float x) {
    float a = fabsf(x);
    float t = 1.f - 2.f / (__expf(2.f * a) + 1.f);
    return copysignf(t, x);
}
__device__ __forceinline__ uint2 gload2u(const unsigned short* p) {
    uint2 r;
    asm volatile("global_load_dwordx2 %0, %1, off" : "=v"(r) : "v"(p) : "memory");
    return r;
}

// ---------------- Fused: 3x input-projection GEMMs + W_hh fragment pack.
// Blocks 0..767: MFMA GEMM (NT), permuted bf16 output
//   (stored col n = w*64 + q*4 + g  <->  orig gate-col g*256 + w*16 + q).
// Blocks 768..959: W_hh (4H,H) fp32 -> MFMA-B-fragment-linear bf16 (for lstm6).
__global__ __launch_bounds__(512)
void k_mm_all(const float* __restrict__ A0, const float* __restrict__ A1,
              const float* __restrict__ A2,
              const float* __restrict__ W0, const float* __restrict__ W1,
              const float* __restrict__ W2,
              const float* __restrict__ bi0, const float* __restrict__ bi1,
              const float* __restrict__ bi2,
              const float* __restrict__ bh0, const float* __restrict__ bh1,
              const float* __restrict__ bh2,
              unsigned short* __restrict__ C0, unsigned short* __restrict__ C1,
              unsigned short* __restrict__ C2,
              const float* __restrict__ wa, const float* __restrict__ wv,
              const float* __restrict__ wtx, unsigned int* __restrict__ wfrag) {
    const int bx  = blockIdx.x;
    const int tid = threadIdx.x;

    if (bx >= 768) {
        // ---- W_hh fragment pack: g = (net, w, s, gate, lane)
        int g = (bx - 768) * 512 + tid;     // 0 .. 98303
        int l  = g & 63;
        int gt = (g >> 6) & 3;
        int s  = (g >> 8) & 7;
        int w  = (g >> 11) & 15;
        int net = g >> 15;
        const float* W = (net == 0) ? wa : (net == 1) ? wv : wtx;
        const int col = gt * 256 + w * 16 + (l & 15);
        const int k0  = s * 32 + (l >> 4) * 8;
        const float* src = W + (size_t)col * 256 + k0;
        float4 f0 = *(const float4*)src;
        float4 f1 = *(const float4*)(src + 4);
        u32x4 v = { pack2bf(f0.x, f0.y), pack2bf(f0.z, f0.w),
                    pack2bf(f1.x, f1.y), pack2bf(f1.z, f1.w) };
        *(u32x4*)&wfrag[(size_t)g * 4] = v;
        return;
    }

    // ---- input projection GEMM
    const int net = bx >> 8;
    const int mt  = (bx & 255) >> 3;
    const int nt  = bx & 7;
    const float* A  = (net == 0) ? A0 : (net == 1) ? A1 : A2;
    const float* W  = (net == 0) ? W0 : (net == 1) ? W1 : W2;
    const float* b1 = (net == 0) ? bi0 : (net == 1) ? bi1 : bi2;
    const float* b2 = (net == 0) ? bh0 : (net == 1) ? bh1 : bh2;
    unsigned short* C = (net == 0) ? C0 : (net == 1) ? C1 : C2;
    const int K = (net == 0) ? 128 : (net == 1) ? 256 : 768;

    __shared__ __align__(16) unsigned int As[256 * 20];
    __shared__ __align__(16) unsigned int Bs[128 * 20];
    const int lane = tid & 63;
    const int wid  = tid >> 6;
    const int wm   = wid >> 1, wn = wid & 1;
    const int m0 = mt * 256, n0 = nt * 128;
    const int nstep = K >> 5;

    const int ar = tid >> 1, akq = (tid & 1) * 16;
    const int br = tid >> 2, bkq = (tid & 3) * 8;
    const float* ap = A + (size_t)(m0 + ar) * K + akq;
    const int nn = n0 + br;
    const int worow = (nn & 3) * 256 + (nn >> 6) * 16 + ((nn >> 2) & 15);
    const float* wp = W + (size_t)worow * K + bkq;

    float4 aR[4], bR[2];
    auto loadA = [&](int s) {
#pragma unroll
        for (int i = 0; i < 4; ++i) aR[i] = *(const float4*)(ap + s * 32 + i * 4);
    };
    auto loadB = [&](int s) {
#pragma unroll
        for (int i = 0; i < 2; ++i) bR[i] = *(const float4*)(wp + s * 32 + i * 4);
    };

    f32x4 acc[4][4];
#pragma unroll
    for (int i = 0; i < 4; ++i)
#pragma unroll
        for (int j = 0; j < 4; ++j) acc[i][j] = (f32x4){0.f, 0.f, 0.f, 0.f};

    loadA(0); loadB(0);
    for (int s = 0; s < nstep; ++s) {
        __syncthreads();
        {
            u32x4 w0 = { pack2bf(aR[0].x, aR[0].y), pack2bf(aR[0].z, aR[0].w),
                         pack2bf(aR[1].x, aR[1].y), pack2bf(aR[1].z, aR[1].w) };
            u32x4 w1 = { pack2bf(aR[2].x, aR[2].y), pack2bf(aR[2].z, aR[2].w),
                         pack2bf(aR[3].x, aR[3].y), pack2bf(aR[3].z, aR[3].w) };
            *(u32x4*)&As[ar * 20 + (akq >> 1)]     = w0;
            *(u32x4*)&As[ar * 20 + (akq >> 1) + 4] = w1;
            u32x4 v0 = { pack2bf(bR[0].x, bR[0].y), pack2bf(bR[0].z, bR[0].w),
                         pack2bf(bR[1].x, bR[1].y), pack2bf(bR[1].z, bR[1].w) };
            *(u32x4*)&Bs[br * 20 + (bkq >> 1)] = v0;
        }
        __syncthreads();
        if (s + 1 < nstep) { loadA(s + 1); loadB(s + 1); }
        short8 af[4], bf[4];
#pragma unroll
        for (int i = 0; i < 4; ++i)
            af[i] = __builtin_bit_cast(short8,
                *(const u32x4*)&As[(wm * 64 + i * 16 + (lane & 15)) * 20 + (lane >> 4) * 4]);
#pragma unroll
        for (int j = 0; j < 4; ++j)
            bf[j] = __builtin_bit_cast(short8,
                *(const u32x4*)&Bs[(wn * 64 + j * 16 + (lane & 15)) * 20 + (lane >> 4) * 4]);
#pragma unroll
        for (int i = 0; i < 4; ++i)
#pragma unroll
            for (int j = 0; j < 4; ++j)
                acc[i][j] = __builtin_amdgcn_mfma_f32_16x16x32_bf16(af[i], bf[j], acc[i][j], 0, 0, 0);
    }
#pragma unroll
    for (int i = 0; i < 4; ++i) {
#pragma unroll
        for (int j = 0; j < 4; ++j) {
            const int col  = n0 + wn * 64 + j * 16 + (lane & 15);
            const int ocol = (col & 3) * 256 + (col >> 6) * 16 + ((col >> 2) & 15);
            const float badd = b1[ocol] + b2[ocol];
#pragma unroll
            for (int e = 0; e < 4; ++e) {
                const int row = m0 + wm * 64 + i * 16 + (lane >> 4) * 4 + e;
                const float v = acc[i][j][e] + badd;
                C[(size_t)row * 1024 + col] =
                    (unsigned short)(__builtin_bit_cast(unsigned int, v) >> 16);
            }
        }
    }
}

// ---------------- k_lstm6: MFMA recurrence, counted-DMA W pipeline (r8/r10-proven).
__global__ __launch_bounds__(1024, 4)
void k_lstm6(const unsigned short* __restrict__ xp_a, const unsigned short* __restrict__ xp_v,
             const unsigned short* __restrict__ xp_t, const unsigned int* __restrict__ wfrag,
             unsigned short* __restrict__ hp) {
    const int bg  = blockIdx.x;            // 0..15
    const int net = blockIdx.y;            // 0=audio,1=video,2=text
    const int tid = threadIdx.x;
    const int l   = tid & 63;
    const int w   = tid >> 6;              // wave -> dim-slice [16w,16w+16)
    const unsigned short* xp = (net == 0) ? xp_a : (net == 1) ? xp_v : xp_t;
    const int coloff = (net == 0) ? 256 : (net == 1) ? 512 : 0;  // cat=[text,audio,video]

    __shared__ __align__(16) unsigned short hA[8192];     // 2 x 8 KB, XOR-swizzled
    __shared__ __align__(16) unsigned int Wring[32768];   // 128 KB: wave w at [w*2048]

    for (int i = tid; i < 4096; i += 1024) ((unsigned int*)hA)[i] = 0u;

    const int q  = l & 15;
    const int r0 = (l >> 4) * 4;           // first of 4 batch rows this lane owns
    const int d  = w * 16 + q;             // dim within net

    const char* wbase = (const char*)wfrag + (size_t)(net * 16 + w) * 32768 + l * 16;
    unsigned int* wslot = &Wring[w * 2048];

    const unsigned short* xr0 = xp + ((size_t)(bg * 16 + r0) * 32) * 1024 + w * 64 + q * 4;

    const unsigned int rbase = (unsigned int)q * 512;
    const unsigned int rxor  = (unsigned int)(q & 7) << 4;
    const unsigned int kofs  = (unsigned int)(l >> 4) * 16;

    float cc[4] = {0.f, 0.f, 0.f, 0.f};

    auto issue_slab = [&](int slab, int slot) {
#pragma unroll
        for (int g = 0; g < 4; ++g) {
            const void* gp = (const void*)(wbase + slab * 4096 + g * 1024);
            void* lp = (void*)(wslot + slot * 1024 + g * 256);
            __builtin_amdgcn_global_load_lds(
                (gas_u32p)(size_t)gp,
                (las_u32p)(unsigned int)(size_t)lp, 16, 0, 0);
        }
    };

    issue_slab(0, 0);
    issue_slab(1, 1);
    asm volatile("s_waitcnt lgkmcnt(0)" ::: "memory");
    __builtin_amdgcn_s_barrier();

    for (int t = 0; t < kT; ++t) {
        const unsigned short* xr = xr0 + (size_t)t * 1024;
        uint2 xq0 = gload2u(xr);
        uint2 xq1 = gload2u(xr + 32768);
        uint2 xq2 = gload2u(xr + 65536);
        uint2 xq3 = gload2u(xr + 98304);

        const unsigned int rbuf = (unsigned int)(t & 1) * 8192;
        const unsigned int wbuf = 8192u - rbuf;

        f32x4 acc[4];
#pragma unroll
        for (int g = 0; g < 4; ++g) acc[g] = (f32x4){0.f, 0.f, 0.f, 0.f};

#pragma unroll
        for (int s = 0; s < 8; ++s) {
            if (s < 2) asm volatile("s_waitcnt vmcnt(8)" ::: "memory");
            else       asm volatile("s_waitcnt vmcnt(4)" ::: "memory");
            __builtin_amdgcn_sched_barrier(0);
            u32x4 af = *(const u32x4*)((const char*)hA + rbuf + rbase
                                       + (((unsigned)(s * 64) + kofs) ^ rxor));
            const unsigned int* wp = wslot + (s & 1) * 1024;
            u32x4 b0 = *(const u32x4*)(wp + 0 * 256 + l * 4);
            u32x4 b1 = *(const u32x4*)(wp + 1 * 256 + l * 4);
            u32x4 b2 = *(const u32x4*)(wp + 2 * 256 + l * 4);
            u32x4 b3 = *(const u32x4*)(wp + 3 * 256 + l * 4);
            acc[0] = __builtin_amdgcn_mfma_f32_16x16x32_bf16(
                __builtin_bit_cast(short8, af), __builtin_bit_cast(short8, b0), acc[0], 0, 0, 0);
            acc[1] = __builtin_amdgcn_mfma_f32_16x16x32_bf16(
                __builtin_bit_cast(short8, af), __builtin_bit_cast(short8, b1), acc[1], 0, 0, 0);
            acc[2] = __builtin_amdgcn_mfma_f32_16x16x32_bf16(
                __builtin_bit_cast(short8, af), __builtin_bit_cast(short8, b2), acc[2], 0, 0, 0);
            acc[3] = __builtin_amdgcn_mfma_f32_16x16x32_bf16(
                __builtin_bit_cast(short8, af), __builtin_bit_cast(short8, b3), acc[3], 0, 0, 0);
            __builtin_amdgcn_sched_barrier(0);
            issue_slab((s + 2) & 7, s & 1);
        }

        asm volatile("s_waitcnt vmcnt(8)" ::: "memory");
        __builtin_amdgcn_sched_barrier(0);

        float hv[4];
        {
            float gi, gf, gg, go;
            gi = acc[0][0] + bflo(xq0.x); gf = acc[1][0] + bfhi(xq0.x);
            gg = acc[2][0] + bflo(xq0.y); go = acc[3][0] + bfhi(xq0.y);
            cc[0] = sigm(gf) * cc[0] + sigm(gi) * tanh_fast(gg); hv[0] = sigm(go) * tanh_fast(cc[0]);
            gi = acc[0][1] + bflo(xq1.x); gf = acc[1][1] + bfhi(xq1.x);
            gg = acc[2][1] + bflo(xq1.y); go = acc[3][1] + bfhi(xq1.y);
            cc[1] = sigm(gf) * cc[1] + sigm(gi) * tanh_fast(gg); hv[1] = sigm(go) * tanh_fast(cc[1]);
            gi = acc[0][2] + bflo(xq2.x); gf = acc[1][2] + bfhi(xq2.x);
            gg = acc[2][2] + bflo(xq2.y); go = acc[3][2] + bfhi(xq2.y);
            cc[2] = sigm(gf) * cc[2] + sigm(gi) * tanh_fast(gg); hv[2] = sigm(go) * tanh_fast(cc[2]);
            gi = acc[0][3] + bflo(xq3.x); gf = acc[1][3] + bfhi(xq3.x);
            gg = acc[2][3] + bflo(xq3.y); go = acc[3][3] + bfhi(xq3.y);
            cc[3] = sigm(gf) * cc[3] + sigm(gi) * tanh_fast(gg); hv[3] = sigm(go) * tanh_fast(cc[3]);
        }

        const int kk = (t & 3) * 768 + coloff + d;
        const int sp2 = kk >> 5;
        unsigned short* hpb = hp +
            ((((size_t)((t >> 2) * 96 + sp2) * 16 + bg) * 64
              + (unsigned)(r0 | (((kk >> 3) & 3) << 4))) * 8 + (kk & 7));
#pragma unroll
        for (int e = 0; e < 4; ++e) {
            const unsigned short hb =
                (unsigned short)(__builtin_bit_cast(unsigned int, hv[e]) >> 16);
            const int row = r0 + e;
            *(unsigned short*)((char*)hA + wbuf + (unsigned)row * 512
                               + (((unsigned)(2 * d)) ^ (((unsigned)(row & 7)) << 4))) = hb;
            hpb[e * 8] = hb;
        }
        asm volatile("s_waitcnt lgkmcnt(0)" ::: "memory");
        __builtin_amdgcn_s_barrier();
    }
}

// ---------------- PTP1 MFMA GEMM (full K, N-split, BK=64):
// Grid (r=16, n=8, bz=2); block computes rows 0..255, cols [bz*64, bz*64+64).
__global__ __launch_bounds__(512)
void k_ptp1_mfma(const unsigned int* __restrict__ hp, const float* __restrict__ factor,
                 float* __restrict__ z1) {
    __shared__ __align__(16) unsigned char Bs[64 * 144];
    const int tid  = threadIdx.x;
    const int lane = tid & 63;
    const int wid  = tid >> 6;
    const int r  = blockIdx.x;
    const int n  = blockIdx.y;
    const int bz = blockIdx.z;         // o-half

    const int bo = tid & 63;           // staged o (local)
    const int bc = tid >> 6;           // d-chunk 0..7 (d = bc*8 + e)
    const float* fp = factor + ((size_t)(n * kR + r) * kD1 + 1 + bc * 8) * kO0 + bz * 64 + bo;
    const unsigned int* ha = hp + (size_t)n * 96 * 4096 + lane * 4;

    f32x4 acc[2][4];
#pragma unroll
    for (int i = 0; i < 2; ++i)
#pragma unroll
        for (int j = 0; j < 4; ++j) acc[i][j] = (f32x4){0.f, 0.f, 0.f, 0.f};

    u32x4 pkb[2];
    u32x4 af[2][2][2];                 // [buf][ks][mfrag]
    auto loadB = [&](int s, int qq) {
        float rv[8];
#pragma unroll
        for (int e = 0; e < 8; ++e)
            rv[e] = fp[((size_t)s * 64 + e) * kO0];
        pkb[qq] = (u32x4){ pack2bf(rv[0], rv[1]), pack2bf(rv[2], rv[3]),
                           pack2bf(rv[4], rv[5]), pack2bf(rv[6], rv[7]) };
    };
    auto loadA = [&](int s, int qq) {
#pragma unroll
        for (int ks = 0; ks < 2; ++ks)
#pragma unroll
            for (int i = 0; i < 2; ++i)
                af[qq][ks][i] = *(const u32x4*)(ha
                    + ((size_t)(s * 32 + ks * 16 + wid * 2 + i)) * 256);
    };
    loadB(0, 0); loadA(0, 0);
#pragma unroll 2
    for (int s = 0; s < 48; ++s) {
        const int qq = s & 1;
        __syncthreads();
        *(u32x4*)(Bs + bo * 144 + bc * 16) = pkb[qq];
        __syncthreads();
        if (s + 1 < 48) { loadB(s + 1, qq ^ 1); loadA(s + 1, qq ^ 1); }
        short8 bf[2][4];
#pragma unroll
        for (int ks = 0; ks < 2; ++ks)
#pragma unroll
            for (int j = 0; j < 4; ++j)
                bf[ks][j] = __builtin_bit_cast(short8,
                    *(const u32x4*)(Bs + (j * 16 + (lane & 15)) * 144
                                    + ks * 64 + (lane >> 4) * 16));
#pragma unroll
        for (int ks = 0; ks < 2; ++ks)
#pragma unroll
            for (int i = 0; i < 2; ++i)
#pragma unroll
                for (int j = 0; j < 4; ++j)
                    acc[i][j] = __builtin_amdgcn_mfma_f32_16x16x32_bf16(
                        __builtin_bit_cast(short8, af[qq][ks][i]), bf[ks][j],
                        acc[i][j], 0, 0, 0);
    }
    const size_t zb = (size_t)n * 256;
#pragma unroll
    for (int i = 0; i < 2; ++i) {
#pragma unroll
        for (int j = 0; j < 4; ++j) {
            const int col = bz * 64 + j * 16 + (lane & 15);
#pragma unroll
            for (int e = 0; e < 4; ++e) {
                const int row = (wid * 2 + i) * 16 + (lane >> 4) * 4 + e;
                z1[((zb + row) * kR + r) * kO0 + col] = acc[i][j][e];
            }
        }
    }
}

// ---------------- PTP1 epilogue: barrier-free, 64 threads (o and o+64 per lane)
__global__ __launch_bounds__(64)
void k_ptp1_post(const float* __restrict__ z1, const float* __restrict__ factor,
                 const float* __restrict__ w, const float* __restrict__ bias,
                 float* __restrict__ f1) {
    const int b = blockIdx.x;
    const int n = blockIdx.y;
    const int o = threadIdx.x;   // handles o and o+64
    float sv0[kR], sv1[kR], nrm[kR];
    const size_t zbase = ((size_t)n * kB + b) * kR * kO0;
#pragma unroll
    for (int r = 0; r < kR; ++r) {
        const size_t zo = zbase + r * kO0 + o;
        const size_t fo = (size_t)(n * kR + r) * kD1 * kO0 + o;
        float v0 = z1[zo] + 0.5f * factor[fo];
        float v1 = z1[zo + 64] + 0.5f * factor[fo + 64];
        float a0 = fabsf(v0), a1 = fabsf(v1);
        float s0 = copysignf(a0 * sqrtf(a0), v0);
        float s1 = copysignf(a1 * sqrtf(a1), v1);
        sv0[r] = s0; sv1[r] = s1;
        float t = s0 * s0 + s1 * s1;
#pragma unroll
        for (int off = 1; off < 64; off <<= 1) t += __shfl_xor(t, off, 64);
        nrm[r] = sqrtf(t);
    }
    float out0 = bias[n * kO0 + o];
    float out1 = bias[n * kO0 + o + 64];
#pragma unroll
    for (int r = 0; r < kR; ++r) {
        const float wr = w[n * kR + r];
        out0 += wr * sv0[r] / nrm[r];
        out1 += wr * sv1[r] / nrm[r];
    }
    f1[((size_t)b * kNW + n) * kO0 + o] = out0;
    f1[((size_t)b * kNW + n) * kO0 + o + 64] = out1;
}

// ---------------- PTP2 GEMM (full K, F2 staged in LDS, M-split 16 rows): z2[b,r,o]
__global__ __launch_bounds__(256)
void k_ptp2_gemm(const float* __restrict__ f1flat, const float* __restrict__ factor2,
                 float* __restrict__ z2) {
    const int b0 = blockIdx.x * 16;    // 16 rows/block, grid.x = 16
    const int r  = blockIdx.y;
    const int tx = threadIdx.x & 63;   // o
    const int ty = threadIdx.x >> 6;   // 0..3 (4 rows each)
    __shared__ float xs[16][128];
    __shared__ float Fs[128][64];
    float acc[4];
#pragma unroll
    for (int i = 0; i < 4; ++i) acc[i] = 0.f;
    const float* F = factor2 + (size_t)r * kD2 * kO1;

    for (int k0 = 0; k0 < kD2; k0 += 128) {
        const int len = min(128, kD2 - k0);
        {
            const int row = threadIdx.x >> 4;        // 0..15
            const int c0  = (threadIdx.x & 15) * 8;  // 0..120
#pragma unroll
            for (int i = 0; i < 8; ++i) {
                int k = k0 + c0 + i;
                float v = (k == 0) ? 0.5f
                        : (k < kD2 ? f1flat[(size_t)(b0 + row) * 1024 + (k - 1)] : 0.f);
                xs[row][c0 + i] = v;
            }
        }
        {
#pragma unroll
            for (int i = 0; i < 8; ++i) {
                const int u  = threadIdx.x + i * 256;
                const int dd = u >> 4;
                const int oc = (u & 15) * 4;
                float4 v = (k0 + dd < kD2)
                    ? *(const float4*)(F + (size_t)(k0 + dd) * kO1 + oc)
                    : make_float4(0.f, 0.f, 0.f, 0.f);
                *(float4*)&Fs[dd][oc] = v;
            }
        }
        __syncthreads();
        for (int dd = 0; dd < len; ++dd) {
            float wv = Fs[dd][tx];
#pragma unroll
            for (int i = 0; i < 4; ++i) acc[i] = fmaf(xs[ty * 4 + i][dd], wv, acc[i]);
        }
        __syncthreads();
    }
#pragma unroll
    for (int i = 0; i < 4; ++i) {
        const int b = b0 + ty * 4 + i;
        z2[((size_t)b * kR + r) * kO1 + tx] = acc[i];
    }
}

// ---------------- PTP2 epilogue -> final output (B,64) fp32
__global__ __launch_bounds__(64)
void k_ptp2_post(const float* __restrict__ z2, const float* __restrict__ w2,
                 const float* __restrict__ b2, float* __restrict__ out) {
    const int b = blockIdx.x;
    const int o = threadIdx.x;
    float sv[kR], nrm[kR];
#pragma unroll
    for (int r = 0; r < kR; ++r) {
        float v = z2[((size_t)b * kR + r) * kO1 + o];
        float a = fabsf(v);
        float s = copysignf(a * sqrtf(a), v);
        sv[r] = s;
        float t = s * s;
#pragma unroll
        for (int off = 1; off < 64; off <<= 1) t += __shfl_xor(t, off, 64);
        nrm[r] = sqrtf(t);
    }
    float acc = b2[o];
#pragma unroll
    for (int r = 0; r < kR; ++r) acc += w2[r] * sv[r] / nrm[r];
    out[(size_t)b * kO1 + o] = acc;
}

// ---------------------------------------------------------------------------
extern "C" void kernel_launch(void* const* d_in, const int* in_sizes, int n_in,
                              void* d_out, int out_size, void* d_ws, size_t ws_size,
                              hipStream_t stream) {
    const float* audio_x  = (const float*)d_in[0];
    const float* video_x  = (const float*)d_in[1];
    const float* text_x   = (const float*)d_in[2];
    const float* aw_ih    = (const float*)d_in[3];
    const float* aw_hh    = (const float*)d_in[4];
    const float* ab_ih    = (const float*)d_in[5];
    const float* ab_hh    = (const float*)d_in[6];
    const float* vw_ih    = (const float*)d_in[7];
    const float* vw_hh    = (const float*)d_in[8];
    const float* vb_ih    = (const float*)d_in[9];
    const float* vb_hh    = (const float*)d_in[10];
    const float* txw_ih   = (const float*)d_in[11];
    const float* txw_hh   = (const float*)d_in[12];
    const float* txb_ih   = (const float*)d_in[13];
    const float* txb_hh   = (const float*)d_in[14];
    const float* l1_factor = (const float*)d_in[15];
    const float* l1_weight = (const float*)d_in[16];
    const float* l1_bias   = (const float*)d_in[17];
    const float* l2_factor = (const float*)d_in[18];
    const float* l2_weight = (const float*)d_in[19];
    const float* l2_bias   = (const float*)d_in[20];

    float* ws = (float*)d_ws;
    // workspace layout (float-index units):
    //   xp_a [0,4M)  xp_v [4M,8M)  xp_t [8M,12M)   (each 8192x1024 bf16)
    //   hp at 12,582,912 (+3,145,728)   wfrag at 15,728,640 (+393,216)
    unsigned short* xp_a = (unsigned short*)ws;
    unsigned short* xp_v = (unsigned short*)(ws + 4194304);
    unsigned short* xp_t = (unsigned short*)(ws + 8388608);
    unsigned short* hp   = (unsigned short*)(ws + 12582912);
    unsigned int* wfrag  = (unsigned int*)(ws + 15728640);
    // post-LSTM aliases (xp buffers dead):
    float* z1 = ws;                            //  4,194,304  (n,b,r,o)
    float* f1 = ws + 8388608;                  //    262,144  (in dead xp_t region)
    float* z2 = ws + 8388608 + 262144;         //    262,144

    // 1) fused: 3x input projections (bf16 out, permuted) + W_hh fragment pack
    k_mm_all<<<960, 512, 0, stream>>>(audio_x, video_x, text_x,
                                      aw_ih, vw_ih, txw_ih,
                                      ab_ih, vb_ih, txb_ih,
                                      ab_hh, vb_hh, txb_hh,
                                      xp_a, xp_v, xp_t,
                                      aw_hh, vw_hh, txw_hh, wfrag);

    // 2) LSTM recurrence (counted-DMA W pipeline) -> hp (PTP1 fragment-packed)
    k_lstm6<<<dim3(16, 3), 1024, 0, stream>>>(xp_a, xp_v, xp_t, wfrag, hp);

    // 3) PTP layer 1 (full K, N-split over 2 blocks, BK=64)
    k_ptp1_mfma<<<dim3(16, 8, 2), 512, 0, stream>>>((const unsigned int*)hp, l1_factor, z1);
    k_ptp1_post<<<dim3(256, 8), 64, 0, stream>>>(z1, l1_factor, l1_weight, l1_bias, f1);

    // 4) PTP layer 2 -> output
    k_ptp2_gemm<<<dim3(16, 16), 256, 0, stream>>>(f1, l2_factor, z2);
    k_ptp2_post<<<256, 64, 0, stream>>>(z2, l2_weight, l2_bias, (float*)d_out);
}